// Round 9
// baseline (146.244 us; speedup 1.0000x reference)
//
#include <hip/hip_runtime.h>

typedef __bf16 bf16_t;
typedef bf16_t bf16x8 __attribute__((ext_vector_type(8)));
typedef bf16_t bf16x4 __attribute__((ext_vector_type(4)));
typedef float f32x4 __attribute__((ext_vector_type(4)));

#define M_TOK 32768
#define NWIN 128
#define WIN  256

typedef __attribute__((address_space(3))) void* as3p;
typedef const __attribute__((address_space(1))) void* as1p;

__device__ __forceinline__ void gll16(const void* g, void* l) {
    __builtin_amdgcn_global_load_lds((as1p)g, (as3p)l, 16, 0, 0);
}

__device__ __forceinline__ bf16x8 cvt8(f32x4 a, f32x4 b) {
    bf16x8 o;
    o[0] = (bf16_t)a[0]; o[1] = (bf16_t)a[1]; o[2] = (bf16_t)a[2]; o[3] = (bf16_t)a[3];
    o[4] = (bf16_t)b[0]; o[5] = (bf16_t)b[1]; o[6] = (bf16_t)b[2]; o[7] = (bf16_t)b[3];
    return o;
}

// tiny fp32->bf16 weight convert
__global__ __launch_bounds__(256) void wconv(
    const float* __restrict__ wq, const float* __restrict__ wp,
    bf16_t* __restrict__ wqb, bf16_t* __restrict__ wpb)
{
    int i4 = (blockIdx.x * 256 + threadIdx.x) * 4;
    const float* s; bf16_t* dst; int idx;
    if (i4 < 196608) { s = wq; dst = wqb; idx = i4; }
    else             { s = wp; dst = wpb; idx = i4 - 196608; }
    f32x4 v = *(const f32x4*)(s + idx);
    bf16x4 o;
    o[0] = (bf16_t)v[0]; o[1] = (bf16_t)v[1]; o[2] = (bf16_t)v[2]; o[3] = (bf16_t)v[3];
    *(bf16x4*)(dst + idx) = o;
}

// GEMM1: QKV = relu_qk(X @ Wqkv^T). Outputs:
//   Qg [8][32768][32]  (row-major per head, relu)
//   KTg[8][32][32768]  (TRANSPOSED, relu)  -- fragment-ready for kvy
//   VTg[8][32][32768]  (TRANSPOSED, no relu)
__global__ __launch_bounds__(256) void gemm1_qkv(
    const float* __restrict__ X,
    const bf16_t* __restrict__ Wb,
    bf16_t* __restrict__ Qg,
    bf16_t* __restrict__ KTg,
    bf16_t* __restrict__ VTg)
{
    __shared__ float  As[4][128][16];   // 64 fp32-k in 4 panels, 64B rows
    __shared__ bf16_t Bs[2][128][32];   // 64 bf16-k in 2 panels, 64B rows

    const int tid = threadIdx.x;
    const int lane = tid & 63;
    const int wv = tid >> 6;
    const int wm = wv >> 1, wn = wv & 1;
    const int id = blockIdx.x;
    const int sg = id / 48, wsub = id % 48;
    const int m0 = (sg * 8 + (wsub & 7)) * 128;
    const int n0 = (wsub >> 3) * 128;
    const int r = lane & 15, q = lane >> 4;
    const int srow = lane >> 2;

    f32x4 acc[4][4] = {};

    for (int kc = 0; kc < 256; kc += 64) {
#pragma unroll
        for (int p = 0; p < 4; ++p)
#pragma unroll
            for (int g = 0; g < 2; ++g) {
                const int rb = wv * 32 + g * 16;
                gll16(X + (size_t)(m0 + rb + srow) * 256 + kc + p * 16 + (lane & 3) * 4,
                      &As[p][rb][0]);
            }
#pragma unroll
        for (int p = 0; p < 2; ++p)
#pragma unroll
            for (int g = 0; g < 2; ++g) {
                const int rb = wv * 32 + g * 16;
                gll16(Wb + (size_t)(n0 + rb + srow) * 256 + kc + p * 32 + (lane & 3) * 8,
                      &Bs[p][rb][0]);
            }
        __syncthreads();

#pragma unroll
        for (int kk = 0; kk < 64; kk += 32) {
            const int kq = kk + q * 8;
            const int pA = kq >> 4, offA = kq & 15;
            const int pB = kk >> 5;
            bf16x8 a[4], b[4];
#pragma unroll
            for (int i = 0; i < 4; ++i) {
                f32x4 lo = *(const f32x4*)&As[pA][wm * 64 + i * 16 + r][offA];
                f32x4 hi = *(const f32x4*)&As[pA][wm * 64 + i * 16 + r][offA + 4];
                a[i] = cvt8(lo, hi);
            }
#pragma unroll
            for (int j = 0; j < 4; ++j)
                b[j] = *(const bf16x8*)&Bs[pB][wn * 64 + j * 16 + r][q * 8];
#pragma unroll
            for (int i = 0; i < 4; ++i)
#pragma unroll
                for (int j = 0; j < 4; ++j)   // swapped: col-field->token(r), row-field->n(q*4+reg)
                    acc[i][j] = __builtin_amdgcn_mfma_f32_16x16x32_bf16(b[j], a[i], acc[i][j], 0, 0, 0);
        }
        __syncthreads();
    }

#pragma unroll
    for (int i = 0; i < 4; ++i) {
        const int rowg = m0 + wm * 64 + i * 16 + r;
#pragma unroll
        for (int j = 0; j < 4; ++j) {
            const int nbase = n0 + wn * 64 + j * 16 + q * 4;   // block-uniform range
            if (nbase < 256) {
                // Q: vector store, relu
                const int hq = nbase >> 5, d = nbase & 31;
                bf16x4 o;
#pragma unroll
                for (int reg = 0; reg < 4; ++reg)
                    o[reg] = (bf16_t)fmaxf(acc[i][j][reg], 0.0f);
                *(bf16x4*)&Qg[((size_t)hq * M_TOK + rowg) * 32 + d] = o;
            } else if (nbase < 512) {
                // K transposed: scalar stores KTg[h][c][tok], relu
                const int hh = (nbase >> 5) - 8, c0 = nbase & 31;
#pragma unroll
                for (int reg = 0; reg < 4; ++reg)
                    KTg[((size_t)hh * 32 + c0 + reg) * M_TOK + rowg] =
                        (bf16_t)fmaxf(acc[i][j][reg], 0.0f);
            } else {
                // V transposed: scalar stores VTg[h][d][tok]
                const int hh = (nbase >> 5) - 16, c0 = nbase & 31;
#pragma unroll
                for (int reg = 0; reg < 4; ++reg)
                    VTg[((size_t)hh * 32 + c0 + reg) * M_TOK + rowg] =
                        (bf16_t)acc[i][j][reg];
            }
        }
    }
}

// GEMM2: Out = Y @ Wproj^T + b, Y bf16 [32768,256], Out fp32.
__global__ __launch_bounds__(256) void gemm2_proj(
    const bf16_t* __restrict__ Y,
    const bf16_t* __restrict__ Wb,
    const float* __restrict__ bias,
    float* __restrict__ Out)
{
    __shared__ bf16_t As[2][128][32];
    __shared__ bf16_t Bs[2][128][32];

    const int tid = threadIdx.x;
    const int lane = tid & 63;
    const int wv = tid >> 6;
    const int wm = wv >> 1, wn = wv & 1;
    const int id = blockIdx.x;
    const int sg = id / 32, wsub = id % 32;
    const int m0 = (sg * 16 + (wsub & 15)) * 128;
    const int n0 = (wsub >> 4) * 128;
    const int r = lane & 15, q = lane >> 4;
    const int srow = lane >> 2;

    f32x4 acc[4][4] = {};

    for (int kc = 0; kc < 256; kc += 64) {
#pragma unroll
        for (int p = 0; p < 2; ++p)
#pragma unroll
            for (int g = 0; g < 2; ++g) {
                const int rb = wv * 32 + g * 16;
                gll16(Y + (size_t)(m0 + rb + srow) * 256 + kc + p * 32 + (lane & 3) * 8,
                      &As[p][rb][0]);
                gll16(Wb + (size_t)(n0 + rb + srow) * 256 + kc + p * 32 + (lane & 3) * 8,
                      &Bs[p][rb][0]);
            }
        __syncthreads();

#pragma unroll
        for (int kk = 0; kk < 64; kk += 32) {
            const int pB = kk >> 5;
            bf16x8 a[4], b[4];
#pragma unroll
            for (int i = 0; i < 4; ++i)
                a[i] = *(const bf16x8*)&As[pB][wm * 64 + i * 16 + r][q * 8];
#pragma unroll
            for (int j = 0; j < 4; ++j)
                b[j] = *(const bf16x8*)&Bs[pB][wn * 64 + j * 16 + r][q * 8];
#pragma unroll
            for (int i = 0; i < 4; ++i)
#pragma unroll
                for (int j = 0; j < 4; ++j)
                    acc[i][j] = __builtin_amdgcn_mfma_f32_16x16x32_bf16(b[j], a[i], acc[i][j], 0, 0, 0);
        }
        __syncthreads();
    }

#pragma unroll
    for (int i = 0; i < 4; ++i) {
        const int rowg = m0 + wm * 64 + i * 16 + r;
#pragma unroll
        for (int j = 0; j < 4; ++j) {
            const int nb = n0 + wn * 64 + j * 16 + q * 4;
            f32x4 bi = *(const f32x4*)(bias + nb);
            f32x4 o;
#pragma unroll
            for (int reg = 0; reg < 4; ++reg) o[reg] = acc[i][j][reg] + bi[reg];
            *(f32x4*)&Out[(size_t)rowg * 256 + nb] = o;
        }
    }
}

// Fused per-(window,head) linear attention; K/V fragments DIRECT from
// transposed global layout (no LDS transpose), s via ones-operand MFMA.
__global__ __launch_bounds__(256) void kvy_kernel(
    const bf16_t* __restrict__ Qg,    // [8][32768][32]
    const bf16_t* __restrict__ KTg,   // [8][32][32768]
    const bf16_t* __restrict__ VTg,   // [8][32][32768]
    const int* __restrict__ offsets,
    const int* __restrict__ counts,
    bf16_t* __restrict__ Y)           // [32768,256]
{
    const int w = blockIdx.x;
    const int h = blockIdx.y;
    const int is64 = (counts[1] == 0) ? 1 : 0;
    const int off = offsets[w << is64];
    const int tid = threadIdx.x;
    const int lane = tid & 63;
    const int wv = tid >> 6;
    const int r = lane & 15, q = lane >> 4;

    __shared__ __align__(16) bf16_t KVT[32 * 40];  // KVT[d][c]
    __shared__ float sbuf[32];
    __shared__ float zinv[WIN];

    // P1: KV = K^T V (MFMA, frags from global) + s = K^T 1 (ones-MFMA)
    {
        const int i = wv >> 1, j = wv & 1;
        bf16x8 ones;
#pragma unroll
        for (int u = 0; u < 8; ++u) ones[u] = (bf16_t)1.0f;
        f32x4 acc = {}, accs = {};
        const bf16_t* kr = KTg + ((size_t)h * 32 + i * 16 + r) * M_TOK + off + q * 8;
        const bf16_t* vr = VTg + ((size_t)h * 32 + j * 16 + r) * M_TOK + off + q * 8;
#pragma unroll
        for (int ch = 0; ch < 8; ++ch) {
            bf16x8 af = *(const bf16x8*)(kr + ch * 32);
            bf16x8 bf_ = *(const bf16x8*)(vr + ch * 32);
            acc  = __builtin_amdgcn_mfma_f32_16x16x32_bf16(af, bf_, acc, 0, 0, 0);
            accs = __builtin_amdgcn_mfma_f32_16x16x32_bf16(af, ones, accs, 0, 0, 0);
        }
        // D[m=c][n=d]: col=r -> d=j*16+r, row=q*4+reg -> c=i*16+q*4+reg
        bf16x4 kv4;
#pragma unroll
        for (int reg = 0; reg < 4; ++reg) kv4[reg] = (bf16_t)acc[reg];
        *(bf16x4*)(&KVT[(j * 16 + r) * 40 + i * 16 + q * 4]) = kv4;
        // accs: all cols equal; waves j==0, lane col r==0 write s[c]
        if (j == 0 && r == 0) {
#pragma unroll
            for (int reg = 0; reg < 4; ++reg)
                sbuf[i * 16 + q * 4 + reg] = accs[reg];
        }
    }
    __syncthreads();

    // P2: zinv[t] = 1/(q[t].s + eps)
    {
        const int t = tid;
        const bf16_t* qp = Qg + ((size_t)h * M_TOK + off + t) * 32;
        float z = 0.f;
#pragma unroll
        for (int u = 0; u < 4; ++u) {
            bf16x8 qq = *(const bf16x8*)(qp + u * 8);
#pragma unroll
            for (int jj = 0; jj < 8; ++jj) z += (float)qq[jj] * sbuf[u * 8 + jj];
        }
        zinv[t] = 1.0f / (z + 1e-3f);
    }
    __syncthreads();

    // P3: y = (Q.KV)*zinv, swapped MFMA (col-field->token, row-field->d)
    {
        bf16x8 b0 = *(const bf16x8*)(&KVT[(r) * 40 + q * 8]);
        bf16x8 b1 = *(const bf16x8*)(&KVT[(16 + r) * 40 + q * 8]);
#pragma unroll
        for (int u = 0; u < 4; ++u) {
            const int mi = wv * 4 + u;
            const bf16_t* ap = Qg + ((size_t)h * M_TOK + off + mi * 16 + r) * 32 + q * 8;
            bf16x8 af = *(const bf16x8*)ap;
            f32x4 acc0 = {}, acc1 = {};
            acc0 = __builtin_amdgcn_mfma_f32_16x16x32_bf16(b0, af, acc0, 0, 0, 0);
            acc1 = __builtin_amdgcn_mfma_f32_16x16x32_bf16(b1, af, acc1, 0, 0, 0);
            const int tkn = mi * 16 + r;
            const float zi = zinv[tkn];
            bf16_t* yp = Y + (size_t)(off + tkn) * 256 + h * 32;
            bf16x4 o0, o1;
#pragma unroll
            for (int reg = 0; reg < 4; ++reg) {
                o0[reg] = (bf16_t)(acc0[reg] * zi);
                o1[reg] = (bf16_t)(acc1[reg] * zi);
            }
            *(bf16x4*)(yp + q * 4) = o0;
            *(bf16x4*)(yp + 16 + q * 4) = o1;
        }
    }
}

extern "C" void kernel_launch(void* const* d_in, const int* in_sizes, int n_in,
                              void* d_out, int out_size, void* d_ws, size_t ws_size,
                              hipStream_t stream) {
    const float* x      = (const float*)d_in[0];
    const float* w_qkv  = (const float*)d_in[1];
    const float* w_proj = (const float*)d_in[2];
    const float* b_proj = (const float*)d_in[3];
    const int*   offs   = (const int*)d_in[4];
    const int*   cnts   = (const int*)d_in[5];

    char* ws = (char*)d_ws;
    bf16_t* Qg  = (bf16_t*)ws;                    // 8*32768*32*2 = 16777216 B
    bf16_t* KTg = (bf16_t*)(ws + 16777216);       // 16777216 B
    bf16_t* VTg = (bf16_t*)(ws + 33554432);       // 16777216 B
    bf16_t* Y   = (bf16_t*)(ws + 50331648);       // 16777216 B
    bf16_t* Wqb = (bf16_t*)(ws + 67108864);       //   393216 B
    bf16_t* Wpb = (bf16_t*)(ws + 67502080);       //   131072 B
    float*  out = (float*)d_out;

    wconv<<<256, 256, 0, stream>>>(w_qkv, w_proj, Wqb, Wpb);

    gemm1_qkv<<<1536, 256, 0, stream>>>(x, Wqb, Qg, KTg, VTg);

    kvy_kernel<<<dim3(NWIN, 8), 256, 0, stream>>>(Qg, KTg, VTg, offs, cnts, Y);

    gemm2_proj<<<512, 256, 0, stream>>>(Y, Wpb, b_proj, out);
}